// Round 6
// baseline (74.796 us; speedup 1.0000x reference)
//
#include <hip/hip_runtime.h>
#include <math.h>

// CapsuleLayer routing via MFMA (u_hat never materialized):
//   logit[n,m] = in[n,:] @ cumwv[:,m]     (K=16 bf16 MFMA, C: row=n,col=m)
//   e = exp2(logit)   (cumwv prescaled by log2 e)
//   xc[m,d] = sum_n e[n,m] in[n,d]; S[m] = sum_n e[n,m]   (E^T @ in, MFMA)
//   s = (xc/S) @ W_m (fp32 tail); v = squash(s); cumwv += W_m @ v
//
// R22: workgroup-count experiment. Every variant to date (R15..R21) used
// grid=128 and all in-kernel edits were invisible (+-1us) while the kernel
// window stays ~25us vs a ~6us instruction model. Cold profiles (R18/R19):
// 131-135us dispatch window at ~1% occupancy ~= 1us/WG placement for
// 1024-thread ~100KB-LDS workgroups; steady ~0.2us/WG x 128 ~= the floor.
// Single dispatch-level variable: grid 128 -> 64. One block now computes
// BOTH m-halves of its b:
//  - cumT[32][24]; two B-frags bc0/bc1; per t-iter 4 logit MFMAs
//    (a0/a1 x bc0/bc1) + 2 xc MFMAs (one per m-half; e-exchange applied
//    per half, identical lane topology).
//  - scratch widened: xc[m*17+d] m=0..31, S at [544+m]  (16x576 floats).
//  - tail = 512 threads, m=0..31; tbx[8][64]; out covers all 32 m.
//  - input read once per b (8 MB total, was 16).
// LDS ~= 104 KB -> still 1 block/CU. All verified machinery unchanged.

#define TPB 1024
#define LOG2E 1.44269504088896f

typedef __attribute__((ext_vector_type(8))) short short8;   // 8 bf16 = 4 VGPR
typedef __attribute__((ext_vector_type(4))) short short4v;  // 4 bf16 = 2 VGPR
typedef __attribute__((ext_vector_type(4))) float float4v;  // MFMA acc

#if defined(__has_builtin)
#if __has_builtin(__builtin_amdgcn_mfma_f32_16x16x16bf16_1k)
#define HAVE_MFMA16 1
#endif
#endif

#define DPP_ADDF(x, ctrl) \
    ((x) + __int_as_float(__builtin_amdgcn_update_dpp( \
        0, __float_as_int(x), (ctrl), 0xF, 0xF, true)))
// quad_perm xor1 = 0xB1, xor2 = 0x4E; row_shl:4 = 0x104, row_shl:8 = 0x108

static __device__ inline unsigned short f2bf(float x) {     // RNE f32->bf16
    unsigned u = __float_as_uint(x);
    return (unsigned short)((u + 0x7FFFu + ((u >> 16) & 1u)) >> 16);
}
static __device__ inline unsigned pk2(float a, float b) {
    return (unsigned)f2bf(a) | ((unsigned)f2bf(b) << 16);
}

__global__ __launch_bounds__(TPB)
void capsule_routing_kernel(const float* __restrict__ in,
                            const float* __restrict__ W,
                            float* __restrict__ out)
{
    __shared__ unsigned short inT[16 * 2056];      // bf16 in^T[d][n]+pad  64.3 KB
    __shared__ float scratch[16][576];             // per-wave multiplex   36.9 KB:
        // pass0:  colsum (fully reduced) [d]  (16 floats)
        // reduce: xc [m*17 + d] (m=0..31), S at [544+m]
    __shared__ unsigned short cumT[32 * 24];       // bf16 cumwv*LOG2E [m][d]
    __shared__ float tbx[8][64];                   // tail broadcast [wt][m&3][d]

    const int tid  = threadIdx.x;
    const int w    = tid >> 6;       // 0..15
    const int l    = tid & 63;
    const int ml   = l & 15;         // MFMA row/col owner index
    const int quad = l >> 4;         // 0..3
    const int b    = blockIdx.x;     // 0..63

    const float4* gin4 = (const float4*)(in + ((size_t)b << 15));

    // ======== LOAD PHASE: issue every global load back-to-back ========
    float4 ga0, ga1, ga2, ga3, gb0, gb1, gb2, gb3;
    {
        const int nb0 = (w << 7);
        ga0 = gin4[(nb0       + ml) * 4 + quad];
        gb0 = gin4[(nb0 + 16  + ml) * 4 + quad];
        ga1 = gin4[(nb0 + 32  + ml) * 4 + quad];
        gb1 = gin4[(nb0 + 48  + ml) * 4 + quad];
        ga2 = gin4[(nb0 + 64  + ml) * 4 + quad];
        gb2 = gin4[(nb0 + 80  + ml) * 4 + quad];
        ga3 = gin4[(nb0 + 96  + ml) * 4 + quad];
        gb3 = gin4[(nb0 + 112 + ml) * 4 + quad];
    }
    // W hoist for tail threads (needed only after first barrier)
    const int m  = tid >> 4;         // tail decode (valid for tid<512): 0..31
    const int tc = tid & 15;
    const int wt = tid >> 6;         // 0..7 for tail threads
    const int mr = m & 3;
    float Wcol[16];                  // W[d][m][tc], d=0..15
    float4 Wr0, Wr1, Wr2, Wr3;       // W[tc][m][0..15]
    if (tid < 512) {
        const float* Wb = &W[(m << 4) + tc];
        #pragma unroll
        for (int d = 0; d < 16; ++d)
            Wcol[d] = Wb[d << 9];
        const float4* Wrow = (const float4*)&W[(tc << 9) + (m << 4)];
        Wr0 = Wrow[0]; Wr1 = Wrow[1]; Wr2 = Wrow[2]; Wr3 = Wrow[3];
    }

    // ======== PROCESS PHASE: colsum + frags + inT transpose ========
#ifdef HAVE_MFMA16
    short4v a0h[4], a1h[4];          // A[n=ml][k=d=quad*4+j]
#else
    short8 a0h[4], a1h[4];           // (fallback unused on gfx950)
#endif
    short8 bih[4];                   // B[k=n_local=quad*8+j][d=ml]
    {
        float cs0 = (ga0.x + gb0.x) + (ga1.x + gb1.x) + (ga2.x + gb2.x) + (ga3.x + gb3.x);
        float cs1 = (ga0.y + gb0.y) + (ga1.y + gb1.y) + (ga2.y + gb2.y) + (ga3.y + gb3.y);
        float cs2 = (ga0.z + gb0.z) + (ga1.z + gb1.z) + (ga2.z + gb2.z) + (ga3.z + gb3.z);
        float cs3 = (ga0.w + gb0.w) + (ga1.w + gb1.w) + (ga2.w + gb2.w) + (ga3.w + gb3.w);

        const float4 gaa[4] = {ga0, ga1, ga2, ga3};
        const float4 gbb[4] = {gb0, gb1, gb2, gb3};
        #pragma unroll
        for (int t = 0; t < 4; ++t) {
            const int nb = (w << 7) + (t << 5);
            const float4 ga = gaa[t];
            const float4 gb = gbb[t];
            const unsigned short a0 = f2bf(ga.x), a1 = f2bf(ga.y),
                                 a2 = f2bf(ga.z), a3 = f2bf(ga.w);
            const unsigned short b0 = f2bf(gb.x), b1 = f2bf(gb.y),
                                 b2 = f2bf(gb.z), b3 = f2bf(gb.w);
#ifdef HAVE_MFMA16
            short4v av; av[0]=(short)a0; av[1]=(short)a1; av[2]=(short)a2; av[3]=(short)a3;
            short4v bv; bv[0]=(short)b0; bv[1]=(short)b1; bv[2]=(short)b2; bv[3]=(short)b3;
            a0h[t] = av; a1h[t] = bv;
#else
            short8 av = {0,0,0,0,0,0,0,0}, bv = {0,0,0,0,0,0,0,0};
            a0h[t] = av; a1h[t] = bv;
#endif
            // inT transpose writes: d-row = quad*4+j, col n
            const int dbase = quad * 4;
            inT[(dbase + 0) * 2056 + nb + ml]      = a0;
            inT[(dbase + 1) * 2056 + nb + ml]      = a1;
            inT[(dbase + 2) * 2056 + nb + ml]      = a2;
            inT[(dbase + 3) * 2056 + nb + ml]      = a3;
            inT[(dbase + 0) * 2056 + nb + 16 + ml] = b0;
            inT[(dbase + 1) * 2056 + nb + 16 + ml] = b1;
            inT[(dbase + 2) * 2056 + nb + 16 + ml] = b2;
            inT[(dbase + 3) * 2056 + nb + 16 + ml] = b3;
            // B-frag: rows nb..nb+31 all written this iteration by this
            // wave -> in-order ds write->read, no barrier.
            bih[t] = *(const short8*)&inT[ml * 2056 + nb + quad * 8];
        }
        // colsum reduce over the 16 ml-lanes of each quad-row (VALU DPP)
        cs0 = DPP_ADDF(cs0, 0xB1); cs0 = DPP_ADDF(cs0, 0x4E);
        cs1 = DPP_ADDF(cs1, 0xB1); cs1 = DPP_ADDF(cs1, 0x4E);
        cs2 = DPP_ADDF(cs2, 0xB1); cs2 = DPP_ADDF(cs2, 0x4E);
        cs3 = DPP_ADDF(cs3, 0xB1); cs3 = DPP_ADDF(cs3, 0x4E);
        cs0 = DPP_ADDF(cs0, 0x104); cs0 = DPP_ADDF(cs0, 0x108);
        cs1 = DPP_ADDF(cs1, 0x104); cs1 = DPP_ADDF(cs1, 0x108);
        cs2 = DPP_ADDF(cs2, 0x104); cs2 = DPP_ADDF(cs2, 0x108);
        cs3 = DPP_ADDF(cs3, 0x104); cs3 = DPP_ADDF(cs3, 0x108);
        if ((l & 15) == 0) {
            float4 v4; v4.x = cs0; v4.y = cs1; v4.z = cs2; v4.w = cs3;
            *(float4*)&scratch[w][quad * 4] = v4;  // scratch[w][d]
        }
    }

    // e-exchange constants (verified; within-wave topology, same per m-half)
    const int srcAB = ml + ((quad == 0) ? 16 : (quad == 1) ? 32 : 0);
    const int srcCD = ml + ((quad == 1) ? 48 : (quad == 3) ? 32 : 16);
    const bool selAB = (quad == 1) || (quad == 2);
    const bool selC  = (quad == 3);

    float cwv = 0.f;   // tail threads: cumulative wv[m][d=tc], fp32

    for (int pass = 0; pass < 3; ++pass) {
        // ---------- sweep (passes 1,2): MFMA chunks of 32 n, both m-halves --
        if (pass) {
#ifdef HAVE_MFMA16
            const short4v bc0 = *(const short4v*)&cumT[ml * 24 + quad * 4];
            const short4v bc1 = *(const short4v*)&cumT[(16 + ml) * 24 + quad * 4];
#else
            short8 bc0 = {0,0,0,0,0,0,0,0}, bc1 = {0,0,0,0,0,0,0,0};
            if (quad < 2) {
                bc0 = *(const short8*)&cumT[ml * 24 + quad * 8];
                bc1 = *(const short8*)&cumT[(16 + ml) * 24 + quad * 8];
            }
#endif
            float4v xc0 = {0.f, 0.f, 0.f, 0.f};
            float4v xc1 = {0.f, 0.f, 0.f, 0.f};
            float Sp0 = 0.f, Sp1 = 0.f;

            #pragma unroll
            for (int t = 0; t < 4; ++t) {
                const float4v z = {0.f, 0.f, 0.f, 0.f};
#ifdef HAVE_MFMA16
                float4v c0 = __builtin_amdgcn_mfma_f32_16x16x16bf16_1k(a0h[t], bc0, z, 0, 0, 0);
                float4v c1 = __builtin_amdgcn_mfma_f32_16x16x16bf16_1k(a1h[t], bc0, z, 0, 0, 0);
                float4v d0 = __builtin_amdgcn_mfma_f32_16x16x16bf16_1k(a0h[t], bc1, z, 0, 0, 0);
                float4v d1 = __builtin_amdgcn_mfma_f32_16x16x16bf16_1k(a1h[t], bc1, z, 0, 0, 0);
#else
                float4v c0 = __builtin_amdgcn_mfma_f32_16x16x32_bf16(a0h[t], bc0, z, 0, 0, 0);
                float4v c1 = __builtin_amdgcn_mfma_f32_16x16x32_bf16(a1h[t], bc0, z, 0, 0, 0);
                float4v d0 = __builtin_amdgcn_mfma_f32_16x16x32_bf16(a0h[t], bc1, z, 0, 0, 0);
                float4v d1 = __builtin_amdgcn_mfma_f32_16x16x32_bf16(a1h[t], bc1, z, 0, 0, 0);
#endif
                // ---- m-half 0 ----
                {
                    float e00 = exp2f(c0[0]), e01 = exp2f(c0[1]),
                          e02 = exp2f(c0[2]), e03 = exp2f(c0[3]);
                    float e10 = exp2f(c1[0]), e11 = exp2f(c1[1]),
                          e12 = exp2f(c1[2]), e13 = exp2f(c1[3]);
                    Sp0 += (e00 + e01) + (e02 + e03) + (e10 + e11) + (e12 + e13);
                    const unsigned d00 = pk2(e00, e01), d01 = pk2(e02, e03);
                    const unsigned d10 = pk2(e10, e11), d11 = pk2(e12, e13);
                    const unsigned RA = (unsigned)__shfl((int)(selAB ? d00 : d10), srcAB);
                    const unsigned RB = (unsigned)__shfl((int)(selAB ? d01 : d11), srcAB);
                    const unsigned RC = (unsigned)__shfl((int)(selC  ? d00 : d10), srcCD);
                    const unsigned RD = (unsigned)__shfl((int)(selC  ? d01 : d11), srcCD);
                    union { unsigned u[4]; short8 s; } ua;
                    ua.u[0] = (quad == 0) ? d00 : (selC ? RC : RA);
                    ua.u[1] = (quad == 0) ? d01 : (selC ? RD : RB);
                    ua.u[2] = (quad == 0) ? RA  : (selC ? d10 : RC);
                    ua.u[3] = (quad == 0) ? RB  : (selC ? d11 : RD);
                    xc0 = __builtin_amdgcn_mfma_f32_16x16x32_bf16(ua.s, bih[t], xc0, 0, 0, 0);
                }
                // ---- m-half 1 ----
                {
                    float e00 = exp2f(d0[0]), e01 = exp2f(d0[1]),
                          e02 = exp2f(d0[2]), e03 = exp2f(d0[3]);
                    float e10 = exp2f(d1[0]), e11 = exp2f(d1[1]),
                          e12 = exp2f(d1[2]), e13 = exp2f(d1[3]);
                    Sp1 += (e00 + e01) + (e02 + e03) + (e10 + e11) + (e12 + e13);
                    const unsigned d00 = pk2(e00, e01), d01 = pk2(e02, e03);
                    const unsigned d10 = pk2(e10, e11), d11 = pk2(e12, e13);
                    const unsigned RA = (unsigned)__shfl((int)(selAB ? d00 : d10), srcAB);
                    const unsigned RB = (unsigned)__shfl((int)(selAB ? d01 : d11), srcAB);
                    const unsigned RC = (unsigned)__shfl((int)(selC  ? d00 : d10), srcCD);
                    const unsigned RD = (unsigned)__shfl((int)(selC  ? d01 : d11), srcCD);
                    union { unsigned u[4]; short8 s; } ua;
                    ua.u[0] = (quad == 0) ? d00 : (selC ? RC : RA);
                    ua.u[1] = (quad == 0) ? d01 : (selC ? RD : RB);
                    ua.u[2] = (quad == 0) ? RA  : (selC ? d10 : RC);
                    ua.u[3] = (quad == 0) ? RB  : (selC ? d11 : RD);
                    xc1 = __builtin_amdgcn_mfma_f32_16x16x32_bf16(ua.s, bih[t], xc1, 0, 0, 0);
                }
            }
            // S: reduce over quads (same m = ml / 16+ml)
            Sp0 += __shfl_xor(Sp0, 16);
            Sp0 += __shfl_xor(Sp0, 32);
            Sp1 += __shfl_xor(Sp1, 16);
            Sp1 += __shfl_xor(Sp1, 32);
            #pragma unroll
            for (int r = 0; r < 4; ++r) {
                scratch[w][(quad * 4 + r) * 17 + ml]        = xc0[r];
                scratch[w][(16 + quad * 4 + r) * 17 + ml]   = xc1[r];
            }
            if (l < 16) {
                scratch[w][544 + l]      = Sp0;
                scratch[w][544 + 16 + l] = Sp1;
            }
        }
        __syncthreads();   // scratch slots ready (pass 0: prologue colsum)

        // ---------- tail: 8 waves, thread = (m = 0..31, tc) ----------
        if (tid < 512) {
            float Stot, xtot = 0.f;
            if (pass == 0) {
                Stot = 2048.f;
                #pragma unroll
                for (int w2 = 0; w2 < 16; ++w2)
                    xtot += scratch[w2][tc];
            } else {
                Stot = 0.f;
                #pragma unroll
                for (int w2 = 0; w2 < 16; ++w2) {
                    Stot += scratch[w2][544 + m];
                    xtot += scratch[w2][m * 17 + tc];
                }
            }
            // broadcast xtot(m, all d) to the 16-lane group via tbx
            tbx[wt][mr * 16 + tc] = xtot;
            const float4 x0 = *(const float4*)&tbx[wt][mr * 16 + 0];
            const float4 x1 = *(const float4*)&tbx[wt][mr * 16 + 4];
            const float4 x2 = *(const float4*)&tbx[wt][mr * 16 + 8];
            const float4 x3 = *(const float4*)&tbx[wt][mr * 16 + 12];
            // s(m,tc) = (1/S) sum_d xtot(m,d) * Wcol[d]   (registers)
            float s = x0.x * Wcol[0]  + x0.y * Wcol[1]
                    + x0.z * Wcol[2]  + x0.w * Wcol[3]
                    + x1.x * Wcol[4]  + x1.y * Wcol[5]
                    + x1.z * Wcol[6]  + x1.w * Wcol[7]
                    + x2.x * Wcol[8]  + x2.y * Wcol[9]
                    + x2.z * Wcol[10] + x2.w * Wcol[11]
                    + x3.x * Wcol[12] + x3.y * Wcol[13]
                    + x3.z * Wcol[14] + x3.w * Wcol[15];
            s /= Stot;
            // ONE tbx round-trip of s (squash factor + dots in parallel)
            tbx[wt][mr * 16 + tc] = s;
            const float4 s0 = *(const float4*)&tbx[wt][mr * 16 + 0];
            const float4 s1 = *(const float4*)&tbx[wt][mr * 16 + 4];
            const float4 s2 = *(const float4*)&tbx[wt][mr * 16 + 8];
            const float4 s3 = *(const float4*)&tbx[wt][mr * 16 + 12];
            const float n2 = s0.x*s0.x + s0.y*s0.y + s0.z*s0.z + s0.w*s0.w
                           + s1.x*s1.x + s1.y*s1.y + s1.z*s1.z + s1.w*s1.w
                           + s2.x*s2.x + s2.y*s2.y + s2.z*s2.z + s2.w*s2.w
                           + s3.x*s3.x + s3.y*s3.y + s3.z*s3.z + s3.w*s3.w;
            const float fac = (n2 / (1.f + n2)) / (sqrtf(n2) + 1e-7f);
            if (pass < 2) {
                const float wdot =
                      Wr0.x*s0.x + Wr0.y*s0.y + Wr0.z*s0.z + Wr0.w*s0.w
                    + Wr1.x*s1.x + Wr1.y*s1.y + Wr1.z*s1.z + Wr1.w*s1.w
                    + Wr2.x*s2.x + Wr2.y*s2.y + Wr2.z*s2.z + Wr2.w*s2.w
                    + Wr3.x*s3.x + Wr3.y*s3.y + Wr3.z*s3.z + Wr3.w*s3.w;
                cwv += fac * wdot;
                cumT[m * 24 + tc] = f2bf(cwv * LOG2E);   // m-major
            } else {
                out[((size_t)b << 9) + (m << 4) + tc] = s * fac;
            }
        }
        if (pass < 2) __syncthreads();   // cum ready for next sweep
    }
}

extern "C" void kernel_launch(void* const* d_in, const int* in_sizes, int n_in,
                              void* d_out, int out_size, void* d_ws, size_t ws_size,
                              hipStream_t stream) {
    (void)in_sizes; (void)n_in; (void)d_ws; (void)ws_size; (void)out_size;
    const float* in = (const float*)d_in[0];
    const float* W  = (const float*)d_in[1];
    float* out = (float*)d_out;
    hipLaunchKernelGGL(capsule_routing_kernel, dim3(64), dim3(TPB), 0, stream,
                       in, W, out);
}

// Round 7
// 67.220 us; speedup vs baseline: 1.1127x; 1.1127x over previous
//
#include <hip/hip_runtime.h>
#include <math.h>

// CapsuleLayer routing via MFMA (u_hat never materialized):
//   logit[n,m] = in[n,:] @ cumwv[:,m]     (K=16 bf16 MFMA, C: row=n,col=m)
//   e = exp2(logit)   (cumwv prescaled by log2 e)
//   xc[m,d] = sum_n e[n,m] in[n,d]; S[m] = sum_n e[n,m]   (E^T @ in, MFMA)
//   s = (xc/S) @ W_m (fp32 tail); v = squash(s); cumwv += W_m @ v
//
// R23: e-regroup ELIMINATED. R22 calibration (grid 64, double work ->
// +7us) proved kernel time scales with per-block critical path; R21's
// sweep spends ~1.4us/pass on the LDS pipe (16 ds_bpermute e-regroup +
// scratch per wave, 16 waves, one pipe). Fix: split the xc MFMA into TWO
// K=16 MFMAs. For 16x16x16 the A-frag k-mapping is k=quad*4+j, and the
// logit C-frag already hands lane (quad,ml) e[n=quad*4+r][m=ml] -- the
// A-frag IS the C-frag in place: A1={pk2(e00,e01),pk2(e02,e03)} (c1 ->
// A2 for the n+16 slice). B-frags = two b64 inT reads (k=quad*4+j
// slices), hoisted. Zero DS ops and zero cross-lane ops in the sweep
// loop. k-mapping HW-verified by R18/R21 green runs (bc/a0h use it).
// xcA/xcB dual accumulators break the 8-deep MFMA acc chain.
// Grid back to 128 (R21 config, best = 67.4us).

#define TPB 1024
#define LOG2E 1.44269504088896f

typedef __attribute__((ext_vector_type(8))) short short8;   // 8 bf16 = 4 VGPR
typedef __attribute__((ext_vector_type(4))) short short4v;  // 4 bf16 = 2 VGPR
typedef __attribute__((ext_vector_type(4))) float float4v;  // MFMA acc

#if defined(__has_builtin)
#if __has_builtin(__builtin_amdgcn_mfma_f32_16x16x16bf16_1k)
#define HAVE_MFMA16 1
#endif
#endif

// K=16 MFMA wrapper. Fallback zero-pads to K=32 with CONSISTENT A/B slot
// placement (j -> quad*8+j for both operands) => identical dot product.
static __device__ inline float4v mfma16(short4v a, short4v b, float4v c) {
#ifdef HAVE_MFMA16
    return __builtin_amdgcn_mfma_f32_16x16x16bf16_1k(a, b, c, 0, 0, 0);
#else
    short8 a8 = {a[0], a[1], a[2], a[3], 0, 0, 0, 0};
    short8 b8 = {b[0], b[1], b[2], b[3], 0, 0, 0, 0};
    return __builtin_amdgcn_mfma_f32_16x16x32_bf16(a8, b8, c, 0, 0, 0);
#endif
}

#define DPP_ADDF(x, ctrl) \
    ((x) + __int_as_float(__builtin_amdgcn_update_dpp( \
        0, __float_as_int(x), (ctrl), 0xF, 0xF, true)))
// quad_perm xor1 = 0xB1, xor2 = 0x4E; row_shl:4 = 0x104, row_shl:8 = 0x108

static __device__ inline unsigned short f2bf(float x) {     // RNE f32->bf16
    unsigned u = __float_as_uint(x);
    return (unsigned short)((u + 0x7FFFu + ((u >> 16) & 1u)) >> 16);
}
static __device__ inline unsigned pk2(float a, float b) {
    return (unsigned)f2bf(a) | ((unsigned)f2bf(b) << 16);
}

__global__ __launch_bounds__(TPB)
void capsule_routing_kernel(const float* __restrict__ in,
                            const float* __restrict__ W,
                            float* __restrict__ out)
{
    __shared__ unsigned short inT[16 * 2056];      // bf16 in^T[d][n]+pad  64.3 KB
    __shared__ float scratch[16][320];             // per-wave multiplex   20 KB:
        // pass0:  colsum (fully reduced) [d]  (16 floats)
        // reduce: xc [m*17 + d], S at [272+ml]
    __shared__ unsigned short cumT[16 * 24];       // bf16 cumwv*LOG2E [m][d]
    __shared__ float tbx[4][64];                   // tail broadcast [wt][m&3][d]

    const int tid  = threadIdx.x;
    const int w    = tid >> 6;       // 0..15
    const int l    = tid & 63;
    const int ml   = l & 15;         // MFMA row/col owner index
    const int quad = l >> 4;         // 0..3
    const int b    = blockIdx.x & 63;
    const int m0g  = (blockIdx.x >> 6) << 4;   // 0 or 16

    const float4* gin4 = (const float4*)(in + ((size_t)b << 15));

    // ======== LOAD PHASE: issue every global load back-to-back ========
    float4 ga0, ga1, ga2, ga3, gb0, gb1, gb2, gb3;
    {
        const int nb0 = (w << 7);
        ga0 = gin4[(nb0       + ml) * 4 + quad];
        gb0 = gin4[(nb0 + 16  + ml) * 4 + quad];
        ga1 = gin4[(nb0 + 32  + ml) * 4 + quad];
        gb1 = gin4[(nb0 + 48  + ml) * 4 + quad];
        ga2 = gin4[(nb0 + 64  + ml) * 4 + quad];
        gb2 = gin4[(nb0 + 80  + ml) * 4 + quad];
        ga3 = gin4[(nb0 + 96  + ml) * 4 + quad];
        gb3 = gin4[(nb0 + 112 + ml) * 4 + quad];
    }
    // W hoist for tail threads (needed only after first barrier)
    const int m  = tid >> 4;         // tail decode (valid for tid<256)
    const int tc = tid & 15;
    const int wt = tid >> 6;
    const int mr = m & 3;
    float Wcol[16];                  // W[d][m0g+m][tc], d=0..15
    float4 Wr0, Wr1, Wr2, Wr3;       // W[tc][m0g+m][0..15]
    if (tid < 256) {
        const float* Wb = &W[((m0g + m) << 4) + tc];
        #pragma unroll
        for (int d = 0; d < 16; ++d)
            Wcol[d] = Wb[d << 9];
        const float4* Wrow = (const float4*)&W[(tc << 9) + ((m0g + m) << 4)];
        Wr0 = Wrow[0]; Wr1 = Wrow[1]; Wr2 = Wrow[2]; Wr3 = Wrow[3];
    }

    // ======== PROCESS PHASE: colsum + frags + inT transpose ========
    short4v a0h[4], a1h[4];          // A[n=ml][k=d=quad*4+j]
    short4v bi1h[4], bi2h[4];        // B[k=n_local=quad*4+j][d=ml], halves
    {
        float cs0 = (ga0.x + gb0.x) + (ga1.x + gb1.x) + (ga2.x + gb2.x) + (ga3.x + gb3.x);
        float cs1 = (ga0.y + gb0.y) + (ga1.y + gb1.y) + (ga2.y + gb2.y) + (ga3.y + gb3.y);
        float cs2 = (ga0.z + gb0.z) + (ga1.z + gb1.z) + (ga2.z + gb2.z) + (ga3.z + gb3.z);
        float cs3 = (ga0.w + gb0.w) + (ga1.w + gb1.w) + (ga2.w + gb2.w) + (ga3.w + gb3.w);

        const float4 gaa[4] = {ga0, ga1, ga2, ga3};
        const float4 gbb[4] = {gb0, gb1, gb2, gb3};
        #pragma unroll
        for (int t = 0; t < 4; ++t) {
            const int nb = (w << 7) + (t << 5);
            const float4 ga = gaa[t];
            const float4 gb = gbb[t];
            const unsigned short a0 = f2bf(ga.x), a1 = f2bf(ga.y),
                                 a2 = f2bf(ga.z), a3 = f2bf(ga.w);
            const unsigned short b0 = f2bf(gb.x), b1 = f2bf(gb.y),
                                 b2 = f2bf(gb.z), b3 = f2bf(gb.w);
            short4v av; av[0]=(short)a0; av[1]=(short)a1; av[2]=(short)a2; av[3]=(short)a3;
            short4v bv; bv[0]=(short)b0; bv[1]=(short)b1; bv[2]=(short)b2; bv[3]=(short)b3;
            a0h[t] = av; a1h[t] = bv;
            // inT transpose writes: d-row = quad*4+j, col n
            const int dbase = quad * 4;
            inT[(dbase + 0) * 2056 + nb + ml]      = a0;
            inT[(dbase + 1) * 2056 + nb + ml]      = a1;
            inT[(dbase + 2) * 2056 + nb + ml]      = a2;
            inT[(dbase + 3) * 2056 + nb + ml]      = a3;
            inT[(dbase + 0) * 2056 + nb + 16 + ml] = b0;
            inT[(dbase + 1) * 2056 + nb + 16 + ml] = b1;
            inT[(dbase + 2) * 2056 + nb + 16 + ml] = b2;
            inT[(dbase + 3) * 2056 + nb + 16 + ml] = b3;
            // B-frags (K=16 slices): rows nb..nb+31 all written this
            // iteration by this wave -> in-order ds write->read, no barrier.
            bi1h[t] = *(const short4v*)&inT[ml * 2056 + nb + quad * 4];
            bi2h[t] = *(const short4v*)&inT[ml * 2056 + nb + 16 + quad * 4];
        }
        // colsum reduce over the 16 ml-lanes of each quad-row (VALU DPP)
        cs0 = DPP_ADDF(cs0, 0xB1); cs0 = DPP_ADDF(cs0, 0x4E);
        cs1 = DPP_ADDF(cs1, 0xB1); cs1 = DPP_ADDF(cs1, 0x4E);
        cs2 = DPP_ADDF(cs2, 0xB1); cs2 = DPP_ADDF(cs2, 0x4E);
        cs3 = DPP_ADDF(cs3, 0xB1); cs3 = DPP_ADDF(cs3, 0x4E);
        cs0 = DPP_ADDF(cs0, 0x104); cs0 = DPP_ADDF(cs0, 0x108);
        cs1 = DPP_ADDF(cs1, 0x104); cs1 = DPP_ADDF(cs1, 0x108);
        cs2 = DPP_ADDF(cs2, 0x104); cs2 = DPP_ADDF(cs2, 0x108);
        cs3 = DPP_ADDF(cs3, 0x104); cs3 = DPP_ADDF(cs3, 0x108);
        if ((l & 15) == 0) {
            float4 v4; v4.x = cs0; v4.y = cs1; v4.z = cs2; v4.w = cs3;
            *(float4*)&scratch[w][quad * 4] = v4;  // scratch[w][d]
        }
    }

    float cwv = 0.f;   // tail threads: cumulative wv[m][d=tc], fp32

    for (int pass = 0; pass < 3; ++pass) {
        // ---------- sweep (passes 1,2): MFMA chunks of 32 n ----------
        if (pass) {
            const short4v bc = *(const short4v*)&cumT[ml * 24 + quad * 4];
            float4v xcA = {0.f, 0.f, 0.f, 0.f};
            float4v xcB = {0.f, 0.f, 0.f, 0.f};
            float Sp = 0.f;

            #pragma unroll
            for (int t = 0; t < 4; ++t) {
                const float4v z = {0.f, 0.f, 0.f, 0.f};
                float4v c0 = mfma16(a0h[t], bc, z);
                float4v c1 = mfma16(a1h[t], bc, z);
                // e = exp2(logit); C: row n = quad*4+r, col m = ml
                float e00 = exp2f(c0[0]), e01 = exp2f(c0[1]),
                      e02 = exp2f(c0[2]), e03 = exp2f(c0[3]);
                float e10 = exp2f(c1[0]), e11 = exp2f(c1[1]),
                      e12 = exp2f(c1[2]), e13 = exp2f(c1[3]);
                Sp += (e00 + e01) + (e02 + e03) + (e10 + e11) + (e12 + e13);
                // A-frag(E^T, K=16 slice) IS the packed C-frag in place:
                // A[row=m=ml][k=quad*4+j] = e[n_local=quad*4+j][ml]
                union { unsigned u[2]; short4v s; } A1, A2;
                A1.u[0] = pk2(e00, e01); A1.u[1] = pk2(e02, e03);
                A2.u[0] = pk2(e10, e11); A2.u[1] = pk2(e12, e13);
                xcA = mfma16(A1.s, bi1h[t], xcA);   // n_local 0..15
                xcB = mfma16(A2.s, bi2h[t], xcB);   // n_local 16..31
            }
            // S: reduce over quads (same m = ml)
            Sp += __shfl_xor(Sp, 16);
            Sp += __shfl_xor(Sp, 32);
            #pragma unroll
            for (int r = 0; r < 4; ++r)
                scratch[w][(quad * 4 + r) * 17 + ml] = xcA[r] + xcB[r];
            if (l < 16) scratch[w][272 + l] = Sp;
        }
        __syncthreads();   // scratch slots ready (pass 0: prologue colsum)

        // ---------- tail: 4 waves, thread = (m, tc) ----------
        if (tid < 256) {
            float Stot, xtot = 0.f;
            if (pass == 0) {
                Stot = 2048.f;
                #pragma unroll
                for (int w2 = 0; w2 < 16; ++w2)
                    xtot += scratch[w2][tc];
            } else {
                Stot = 0.f;
                #pragma unroll
                for (int w2 = 0; w2 < 16; ++w2) {
                    Stot += scratch[w2][272 + m];
                    xtot += scratch[w2][m * 17 + tc];
                }
            }
            // broadcast xtot(m, all d) to the 16-lane group via tbx
            tbx[wt][mr * 16 + tc] = xtot;
            const float4 x0 = *(const float4*)&tbx[wt][mr * 16 + 0];
            const float4 x1 = *(const float4*)&tbx[wt][mr * 16 + 4];
            const float4 x2 = *(const float4*)&tbx[wt][mr * 16 + 8];
            const float4 x3 = *(const float4*)&tbx[wt][mr * 16 + 12];
            // s(m,tc) = (1/S) sum_d xtot(m,d) * Wcol[d]   (registers)
            float s = x0.x * Wcol[0]  + x0.y * Wcol[1]
                    + x0.z * Wcol[2]  + x0.w * Wcol[3]
                    + x1.x * Wcol[4]  + x1.y * Wcol[5]
                    + x1.z * Wcol[6]  + x1.w * Wcol[7]
                    + x2.x * Wcol[8]  + x2.y * Wcol[9]
                    + x2.z * Wcol[10] + x2.w * Wcol[11]
                    + x3.x * Wcol[12] + x3.y * Wcol[13]
                    + x3.z * Wcol[14] + x3.w * Wcol[15];
            s /= Stot;
            // ONE tbx round-trip of s (squash factor + dots in parallel)
            tbx[wt][mr * 16 + tc] = s;
            const float4 s0 = *(const float4*)&tbx[wt][mr * 16 + 0];
            const float4 s1 = *(const float4*)&tbx[wt][mr * 16 + 4];
            const float4 s2 = *(const float4*)&tbx[wt][mr * 16 + 8];
            const float4 s3 = *(const float4*)&tbx[wt][mr * 16 + 12];
            const float n2 = s0.x*s0.x + s0.y*s0.y + s0.z*s0.z + s0.w*s0.w
                           + s1.x*s1.x + s1.y*s1.y + s1.z*s1.z + s1.w*s1.w
                           + s2.x*s2.x + s2.y*s2.y + s2.z*s2.z + s2.w*s2.w
                           + s3.x*s3.x + s3.y*s3.y + s3.z*s3.z + s3.w*s3.w;
            const float fac = (n2 / (1.f + n2)) / (sqrtf(n2) + 1e-7f);
            if (pass < 2) {
                const float wdot =
                      Wr0.x*s0.x + Wr0.y*s0.y + Wr0.z*s0.z + Wr0.w*s0.w
                    + Wr1.x*s1.x + Wr1.y*s1.y + Wr1.z*s1.z + Wr1.w*s1.w
                    + Wr2.x*s2.x + Wr2.y*s2.y + Wr2.z*s2.z + Wr2.w*s2.w
                    + Wr3.x*s3.x + Wr3.y*s3.y + Wr3.z*s3.z + Wr3.w*s3.w;
                cwv += fac * wdot;
                cumT[m * 24 + tc] = f2bf(cwv * LOG2E);   // m-major
            } else {
                out[((size_t)b << 9) + ((m0g + m) << 4) + tc] = s * fac;
            }
        }
        if (pass < 2) __syncthreads();   // cum ready for next sweep
    }
}

extern "C" void kernel_launch(void* const* d_in, const int* in_sizes, int n_in,
                              void* d_out, int out_size, void* d_ws, size_t ws_size,
                              hipStream_t stream) {
    (void)in_sizes; (void)n_in; (void)d_ws; (void)ws_size; (void)out_size;
    const float* in = (const float*)d_in[0];
    const float* W  = (const float*)d_in[1];
    float* out = (float*)d_out;
    hipLaunchKernelGGL(capsule_routing_kernel, dim3(128), dim3(TPB), 0, stream,
                       in, W, out);
}